// Round 1
// baseline (171.084 us; speedup 1.0000x reference)
//
#include <hip/hip_runtime.h>
#include <hip/hip_bf16.h>

// Problem constants (fixed-shape per reference)
#define B_SIZE 16384
#define D_DIM  1024
#define T_DIM  128
#define VLn    12          // V*L = 4*3
#define BM     64          // rows per block
#define BK     64          // K-chunk
#define KCHUNKS (D_DIM / BK)   // 16

typedef __attribute__((ext_vector_type(8))) short  short8;  // 8 bf16 (4 VGPRs)
typedef __attribute__((ext_vector_type(4))) float  f32x4;   // MFMA accumulator

// fp32 -> bf16 round-to-nearest-even (inputs are normal floats; no NaN handling needed)
__device__ __forceinline__ unsigned short f2bf(float f) {
    union { float f; unsigned int u; } c; c.f = f;
    unsigned int u = c.u;
    return (unsigned short)((u + 0x7FFFu + ((u >> 16) & 1u)) >> 16);
}

// LDS layout (aliased phases):
//   staging: sA [64][72] bf16 (9216 B) + sW [128][72] bf16 (18432 B) = 27648 B
//   probs:   sP [64][132] f32 = 33792 B
__global__ __launch_bounds__(256)
void qloss_kernel(const float* __restrict__ emb,
                  const float* __restrict__ W,
                  const float* __restrict__ bias,
                  const int*   __restrict__ didx,
                  const int*   __restrict__ dmsk,
                  float*       __restrict__ out)
{
    __shared__ __align__(16) unsigned char smem[33792];
    unsigned short* sA = (unsigned short*)smem;            // [64][72]
    unsigned short* sW = (unsigned short*)(smem + 9216);   // [128][72]
    float*          sP = (float*)smem;                     // [64][132]

    const int t    = threadIdx.x;
    const int w    = t >> 6;       // wave 0..3
    const int lane = t & 63;
    const int m15  = lane & 15;
    const int quad = lane >> 4;
    const int r0   = blockIdx.x * BM;

    f32x4 acc[8];
#pragma unroll
    for (int ct = 0; ct < 8; ++ct) acc[ct] = (f32x4){0.f, 0.f, 0.f, 0.f};

    // staging mapping: 16 threads per row, float4 each
    const int srow = t >> 4;          // base row (add p*16)
    const int sc4  = (t & 15) * 4;    // col within chunk

    for (int kc = 0; kc < KCHUNKS; ++kc) {
        const int kbase = kc * BK;
        __syncthreads();   // previous compute phase done reading LDS
        // stage A: 64x64, convert fp32->bf16
#pragma unroll
        for (int p = 0; p < 4; ++p) {
            const int row = srow + p * 16;
            const float4 v = *(const float4*)(emb + (size_t)(r0 + row) * D_DIM + kbase + sc4);
            ushort4 h; h.x = f2bf(v.x); h.y = f2bf(v.y); h.z = f2bf(v.z); h.w = f2bf(v.w);
            *(ushort4*)(sA + row * 72 + sc4) = h;
        }
        // stage W: 128x64 (L2-resident after first pass over blocks)
#pragma unroll
        for (int p = 0; p < 8; ++p) {
            const int row = srow + p * 16;
            const float4 v = *(const float4*)(W + (size_t)row * D_DIM + kbase + sc4);
            ushort4 h; h.x = f2bf(v.x); h.y = f2bf(v.y); h.z = f2bf(v.z); h.w = f2bf(v.w);
            *(ushort4*)(sW + row * 72 + sc4) = h;
        }
        __syncthreads();
        // compute: two K=32 steps; wave w owns rows w*16..w*16+15, all 128 cols
#pragma unroll
        for (int ks = 0; ks < 2; ++ks) {
            const int ko = ks * 32 + quad * 8;     // A/B operand: [lane&15][quad*8+j]
            short8 a = *(const short8*)(sA + (w * 16 + m15) * 72 + ko);
#pragma unroll
            for (int ct = 0; ct < 8; ++ct) {
                short8 bf = *(const short8*)(sW + (ct * 16 + m15) * 72 + ko);
                acc[ct] = __builtin_amdgcn_mfma_f32_16x16x32_bf16(a, bf, acc[ct], 0, 0, 0);
            }
        }
    }

    // Epilogue. C/D layout: col = ct*16 + (lane&15), row (in wave tile) = quad*4 + i
    float bcol[8];
#pragma unroll
    for (int ct = 0; ct < 8; ++ct) bcol[ct] = bias[ct * 16 + m15];

    float sm[4];
#pragma unroll
    for (int i = 0; i < 4; ++i) {
        float m = -1e30f;
#pragma unroll
        for (int ct = 0; ct < 8; ++ct) { acc[ct][i] += bcol[ct]; m = fmaxf(m, acc[ct][i]); }
        // row max across the 16 lanes of this quad (xor 1,2,4,8 stays in-quad)
#pragma unroll
        for (int off = 1; off < 16; off <<= 1) m = fmaxf(m, __shfl_xor(m, off));
        float s = 0.f;
#pragma unroll
        for (int ct = 0; ct < 8; ++ct) { float e = __expf(acc[ct][i] - m); acc[ct][i] = e; s += e; }
#pragma unroll
        for (int off = 1; off < 16; off <<= 1) s += __shfl_xor(s, off);
        sm[i] = s;
    }

    __syncthreads();   // all waves done with sA/sW before sP overwrites
#pragma unroll
    for (int i = 0; i < 4; ++i) {
        const float inv = 1.0f / sm[i];
        const int row = w * 16 + quad * 4 + i;
#pragma unroll
        for (int ct = 0; ct < 8; ++ct)
            sP[row * 132 + ct * 16 + m15] = acc[ct][i] * inv;
    }
    __syncthreads();

    // gather: 4 threads per row, 3 (idx,mask) entries each
    {
        const int row = t >> 2, sub = t & 3;
        const size_t gbase = (size_t)(r0 + row) * VLn + sub * 3;
        float p = 0.f;
#pragma unroll
        for (int j = 0; j < 3; ++j) {
            const int idx = didx[gbase + j];
            const int mk  = dmsk[gbase + j];
            const float v = sP[row * 132 + idx];
            p += mk ? v : 0.f;
        }
        // full-wave reduce (each lane holds a disjoint partial)
#pragma unroll
        for (int off = 1; off < 64; off <<= 1) p += __shfl_xor(p, off);
        if (lane == 0) atomicAdd(out, p * (1.0f / 65536.0f));  // / (V*B)
    }
}

extern "C" void kernel_launch(void* const* d_in, const int* in_sizes, int n_in,
                              void* d_out, int out_size, void* d_ws, size_t ws_size,
                              hipStream_t stream) {
    const float* emb  = (const float*)d_in[0];
    const float* W    = (const float*)d_in[1];
    const float* bias = (const float*)d_in[2];
    const int*   didx = (const int*)d_in[3];
    const int*   dmsk = (const int*)d_in[4];
    float* out = (float*)d_out;

    hipMemsetAsync(out, 0, sizeof(float), stream);   // graph-capturable memset node
    qloss_kernel<<<B_SIZE / BM, 256, 0, stream>>>(emb, W, bias, didx, dmsk, out);
}

// Round 2
// 131.562 us; speedup vs baseline: 1.3004x; 1.3004x over previous
//
#include <hip/hip_runtime.h>

// Problem constants (fixed-shape per reference)
#define B_SIZE 16384
#define D_DIM  1024
#define T_DIM  128
#define VLn    12        // V*L
#define ROWS   16        // rows per block (one 16-row MFMA tile)
#define KPW    256       // K-range per wave (D_DIM / 4 waves)
#define NCHUNK 8         // KPW / 32

typedef __attribute__((ext_vector_type(8))) short  short8;  // 8 bf16
typedef __attribute__((ext_vector_type(4))) float  f32x4;   // MFMA acc

__device__ __forceinline__ unsigned short f2bf(float f) {
    union { float f; unsigned int u; } c; c.f = f;
    unsigned int u = c.u;
    return (unsigned short)((u + 0x7FFFu + ((u >> 16) & 1u)) >> 16);
}

// One-time (per launch) W fp32 -> bf16 conversion into workspace.
// 128x1024 elems; 128 blocks x 256 threads x 4 elems.
__global__ __launch_bounds__(256)
void conv_w_kernel(const float* __restrict__ W, unsigned short* __restrict__ Wb) {
    const int i = (blockIdx.x * 256 + threadIdx.x) * 4;
    const float4 v = *(const float4*)(W + i);
    ushort4 h; h.x = f2bf(v.x); h.y = f2bf(v.y); h.z = f2bf(v.z); h.w = f2bf(v.w);
    *(ushort4*)(Wb + i) = h;
}

// Main kernel: 1024 blocks x 256 threads (4 waves). Block owns 16 rows.
// Wave w computes partial logits over K in [w*256, w*256+256) with NO LDS
// and NO barriers (per-lane direct global loads of MFMA fragments), then the
// 4 partials are combined in LDS, softmax'd, gathered, and reduced.
// LDS partials layout: [w][16][132] f32 (132-stride -> 2-way conflicts only).
__global__ __launch_bounds__(256, 4)
void qloss_kernel(const float* __restrict__ emb,
                  const unsigned short* __restrict__ Wb,
                  const float* __restrict__ bias,
                  const int*   __restrict__ didx,
                  const int*   __restrict__ dmsk,
                  float*       __restrict__ out)
{
    __shared__ float sP[4 * 16 * 132 + 4];   // 33808 B
    const int t    = threadIdx.x;
    const int w    = t >> 6;
    const int lane = t & 63;
    const int m15  = lane & 15;
    const int quad = lane >> 4;
    const int r0   = blockIdx.x * ROWS;

    f32x4 acc[8];
#pragma unroll
    for (int ct = 0; ct < 8; ++ct) acc[ct] = (f32x4){0.f, 0.f, 0.f, 0.f};

    // Per-lane fragment base pointers.
    // A-frag: A[m = m15][k = kbase + quad*8 + j]  (fp32, cvt inline)
    // B-frag: W[n = ct*16 + m15][k = kbase + quad*8 + j] (bf16 pre-converted)
    const float*          aptr = emb + (size_t)(r0 + m15) * D_DIM + w * KPW + quad * 8;
    const unsigned short* bptr = Wb  + (size_t)m15 * D_DIM        + w * KPW + quad * 8;

#pragma unroll 2
    for (int kc = 0; kc < NCHUNK; ++kc) {
        const int ko = kc * 32;
        const float4 a0 = *(const float4*)(aptr + ko);
        const float4 a1 = *(const float4*)(aptr + ko + 4);
        short8 bf[8];
#pragma unroll
        for (int ct = 0; ct < 8; ++ct)
            bf[ct] = *(const short8*)(bptr + (size_t)ct * 16 * D_DIM + ko);
        short8 a;
        a[0] = (short)f2bf(a0.x); a[1] = (short)f2bf(a0.y);
        a[2] = (short)f2bf(a0.z); a[3] = (short)f2bf(a0.w);
        a[4] = (short)f2bf(a1.x); a[5] = (short)f2bf(a1.y);
        a[6] = (short)f2bf(a1.z); a[7] = (short)f2bf(a1.w);
#pragma unroll
        for (int ct = 0; ct < 8; ++ct)
            acc[ct] = __builtin_amdgcn_mfma_f32_16x16x32_bf16(a, bf[ct], acc[ct], 0, 0, 0);
    }

    // Spill partial logits: C/D layout col = ct*16+m15, row = quad*4+i.
    // Bank check: addr/4 = w*2112 + (quad*4+i)*132 + ct*16 + m15 ->
    // bank = (m15 + 16*(quad&1)) % 32 -> 2-way (free).
#pragma unroll
    for (int ct = 0; ct < 8; ++ct)
#pragma unroll
        for (int i = 0; i < 4; ++i)
            sP[w * 2112 + (quad * 4 + i) * 132 + ct * 16 + m15] = acc[ct][i];
    __syncthreads();

    // Combine partials + softmax. 16 threads per row; thread handles cols s*8..s*8+7.
    const int row = t >> 4;
    const int s   = t & 15;
    {
        float v[8];
#pragma unroll
        for (int j = 0; j < 8; ++j) v[j] = bias[s * 8 + j];
#pragma unroll
        for (int w2 = 0; w2 < 4; ++w2) {
            const float4 p0 = *(const float4*)&sP[w2 * 2112 + row * 132 + s * 8];
            const float4 p1 = *(const float4*)&sP[w2 * 2112 + row * 132 + s * 8 + 4];
            v[0] += p0.x; v[1] += p0.y; v[2] += p0.z; v[3] += p0.w;
            v[4] += p1.x; v[5] += p1.y; v[6] += p1.z; v[7] += p1.w;
        }
        float m = -1e30f;
#pragma unroll
        for (int j = 0; j < 8; ++j) m = fmaxf(m, v[j]);
#pragma unroll
        for (int off = 1; off < 16; off <<= 1) m = fmaxf(m, __shfl_xor(m, off));
        float ssum = 0.f;
#pragma unroll
        for (int j = 0; j < 8; ++j) { v[j] = __expf(v[j] - m); ssum += v[j]; }
#pragma unroll
        for (int off = 1; off < 16; off <<= 1) ssum += __shfl_xor(ssum, off);
        const float inv = 1.0f / ssum;
        // Write normalized probs into the w=0 partial region (each (row,col)
        // slot is read and written by exactly one thread -> no barrier needed
        // between the reads above and these writes).
        float4 q0 = {v[0] * inv, v[1] * inv, v[2] * inv, v[3] * inv};
        float4 q1 = {v[4] * inv, v[5] * inv, v[6] * inv, v[7] * inv};
        *(float4*)&sP[row * 132 + s * 8]     = q0;
        *(float4*)&sP[row * 132 + s * 8 + 4] = q1;
    }
    __syncthreads();

    // Gather: 16 threads per row, first 12 handle the (idx, mask) entries.
    float p = 0.f;
    if (s < 12) {
        const int gi  = (r0 + row) * VLn + s;
        const int idx = didx[gi];
        const int mk  = dmsk[gi];
        p = mk ? sP[row * 132 + idx] : 0.f;
    }
#pragma unroll
    for (int off = 1; off < 64; off <<= 1) p += __shfl_xor(p, off);
    if (lane == 0) sP[4 * 2112 + w] = p;
    __syncthreads();
    if (t == 0) {
        const float tot = sP[8448] + sP[8449] + sP[8450] + sP[8451];
        atomicAdd(out, tot * (1.0f / 65536.0f));   // / (V * B)
    }
}

extern "C" void kernel_launch(void* const* d_in, const int* in_sizes, int n_in,
                              void* d_out, int out_size, void* d_ws, size_t ws_size,
                              hipStream_t stream) {
    const float* emb  = (const float*)d_in[0];
    const float* W    = (const float*)d_in[1];
    const float* bias = (const float*)d_in[2];
    const int*   didx = (const int*)d_in[3];
    const int*   dmsk = (const int*)d_in[4];
    float* out = (float*)d_out;
    unsigned short* Wb = (unsigned short*)d_ws;   // 256 KB bf16 W

    hipMemsetAsync(out, 0, sizeof(float), stream);
    conv_w_kernel<<<(T_DIM * D_DIM) / (256 * 4), 256, 0, stream>>>(W, Wb);
    qloss_kernel<<<B_SIZE / ROWS, 256, 0, stream>>>(emb, Wb, bias, didx, dmsk, out);
}